// Round 7
// baseline (1080.192 us; speedup 1.0000x reference)
//
#include <hip/hip_runtime.h>

#define TNODES 65536
#define NGRAPH 16
#define NNODE  4096
#define INCH   256
#define HID    512

using u16 = unsigned short;
using u32 = unsigned int;
using v8s = __attribute__((ext_vector_type(8))) short;   // 8 bf16 (4 VGPRs)
using v4f = __attribute__((ext_vector_type(4))) float;   // 4 fp32 acc

__device__ __forceinline__ float bf2f(u16 u) {
    union { u32 i; float f; } v; v.i = ((u32)u) << 16; return v.f;
}
__device__ __forceinline__ u16 f2bf(float f) {
    union { float f; u32 i; } v; v.f = f;
    u32 x = v.i;
    return (u16)((x + 0x7fffu + ((x >> 16) & 1u)) >> 16);
}
__device__ __forceinline__ void up4(uint2 p, float* f) {
    f[0] = __uint_as_float(p.x << 16); f[1] = __uint_as_float(p.x & 0xffff0000u);
    f[2] = __uint_as_float(p.y << 16); f[3] = __uint_as_float(p.y & 0xffff0000u);
}
__device__ __forceinline__ uint2 pk4(float a, float b, float c, float d) {
    uint2 r;
    r.x = (u32)f2bf(a) | ((u32)f2bf(b) << 16);
    r.y = (u32)f2bf(c) | ((u32)f2bf(d) << 16);
    return r;
}

#define MFMA(a, b, c) __builtin_amdgcn_mfma_f32_16x16x32_bf16((a), (b), (c), 0, 0, 0)

// async global->LDS, 16B per lane. dest = wave-uniform base + lane*16 (linear).
#define GLD16(gp, sp) __builtin_amdgcn_global_load_lds( \
    (const __attribute__((address_space(1))) u32*)(const void*)(gp), \
    (__attribute__((address_space(3))) u32*)(void*)(sp), 16, 0, 0)

#define CFENCE() asm volatile("" ::: "memory")

// ---------------- fp32 -> bf16 convert, vectorized ----------------
__global__ void k_cvt4(const float* __restrict__ s, u16* __restrict__ d, int n4) {
    for (int i = blockIdx.x * blockDim.x + threadIdx.x; i < n4; i += gridDim.x * blockDim.x) {
        float4 f = ((const float4*)s)[i];
        ((uint2*)d)[i] = pk4(f.x, f.y, f.z, f.w);
    }
}

__global__ void k_zero(float* __restrict__ p, int n) {
    int i = blockIdx.x * 256 + threadIdx.x;
    if (i < n) p[i] = 0.f;
}

// ---------------- sum 4 bf16 partial planes -> bf16 ----------------
__global__ void k_red4(const u16* __restrict__ p, u16* __restrict__ o, int n8) {
    const size_t P = (size_t)NGRAPH * HID * HID;
    for (int i = blockIdx.x * blockDim.x + threadIdx.x; i < n8; i += gridDim.x * blockDim.x) {
        size_t b = (size_t)i * 8;
        float s[8] = {0.f, 0.f, 0.f, 0.f, 0.f, 0.f, 0.f, 0.f};
        #pragma unroll
        for (int ss = 0; ss < 4; ++ss) {
            v8s v = *(const v8s*)(p + ss * P + b);
            const u16* vp = (const u16*)&v;
            #pragma unroll
            for (int j = 0; j < 8; ++j) s[j] += bf2f(vp[j]);
        }
        uint2 lo = pk4(s[0], s[1], s[2], s[3]);
        uint2 hi = pk4(s[4], s[5], s[6], s[7]);
        uint4 w; w.x = lo.x; w.y = lo.y; w.z = hi.x; w.w = hi.y;
        *(uint4*)(o + b) = w;
    }
}

// =====================================================================
// GEMM core v3: C[128 x 512] = Act[128 rows, stride LDK] @ W[512 rows]^T.
// 512 threads = 8 waves (2 row-groups x 4 col-groups), wave tile 64x128
// (acc[8][4]). A-operand goes GLOBAL -> REGISTERS directly (the fragment
// pattern is a clean v8s load; 4 q-lanes/row fetch 64B contiguous), double
// buffered in two NAMED reg arrays (rule #20). W stays in LDS (x2 row-group
// reuse): 2x32KB double buffer via global_load_lds(16B), XOR-swizzled.
// Per-CU LDS traffic/step: 136KB -> 96KB (was the port-BW wall at 21% Mfma).
// Counted vmcnt(8) covers {A(k+1),W(k+1)} in flight; drain only at the end.
// =====================================================================
template<int LDK, int KLEN>
__device__ __forceinline__ void gemm_core(const u16* __restrict__ A,
                                          const u16* __restrict__ W,
                                          u16* sW, v4f (&acc)[8][4]) {
    const int t = threadIdx.x, lane = t & 63;
    const int q = lane >> 4, m15 = lane & 15;
    const int w = t >> 6, wr = w >> 2, wc = w & 3;

    #pragma unroll
    for (int n = 0; n < 8; ++n)
        #pragma unroll
        for (int rt = 0; rt < 4; ++rt)
            #pragma unroll
            for (int e = 0; e < 4; ++e) acc[n][rt][e] = 0.f;

    int woff[8];
    #pragma unroll
    for (int n = 0; n < 8; ++n) {
        int r = wc * 128 + n * 16 + m15;
        woff[n] = r * 32 + ((q ^ ((r >> 1) & 3)) * 8);
    }
    const u16* aptr[4];
    #pragma unroll
    for (int rt = 0; rt < 4; ++rt)
        aptr[rt] = A + (size_t)(wr * 64 + rt * 16 + m15) * LDK + q * 8;

    auto stageW = [&](int k0, int buf) {
        u16* dW = sW + buf * (512 * 32);
        #pragma unroll
        for (int p = 0; p < 4; ++p) {
            int sf = p * 512 + t, row = sf >> 2, sl = sf & 3;
            int gc = k0 + ((sl ^ ((row >> 1) & 3)) * 8);
            GLD16(W + (size_t)row * LDK + gc, dW + sf * 8);
        }
    };

    const int KT = KLEN / 32;
    v8s arA[4], arB[4];
    // prologue order W0,A0,W1,A1 -> vmcnt(8) drains {W0,A0}
    stageW(0, 0);
    #pragma unroll
    for (int rt = 0; rt < 4; ++rt) arA[rt] = *(const v8s*)(aptr[rt]);
    stageW(32, 1);
    #pragma unroll
    for (int rt = 0; rt < 4; ++rt) arB[rt] = *(const v8s*)(aptr[rt] + 32);

    #define GSTEP(KTI, AR, BUF)                                              \
    {                                                                        \
        if ((KTI) + 1 < KT) asm volatile("s_waitcnt vmcnt(8)" ::: "memory"); \
        else                asm volatile("s_waitcnt vmcnt(0)" ::: "memory"); \
        __builtin_amdgcn_s_barrier();                                        \
        CFENCE();                                                            \
        __builtin_amdgcn_sched_barrier(0);                                   \
        const u16* cW = sW + (BUF) * (512 * 32);                             \
        _Pragma("unroll")                                                    \
        for (int n = 0; n < 8; ++n) {                                        \
            v8s af = *(const v8s*)(cW + woff[n]);                            \
            _Pragma("unroll")                                                \
            for (int rt = 0; rt < 4; ++rt)                                   \
                acc[n][rt] = MFMA(af, AR[rt], acc[n][rt]);                   \
        }                                                                    \
        CFENCE();                                                            \
        if ((KTI) + 2 < KT) {                                                \
            _Pragma("unroll")                                                \
            for (int rt = 0; rt < 4; ++rt)                                   \
                AR[rt] = *(const v8s*)(aptr[rt] + ((KTI) + 2) * 32);         \
        }                                                                    \
        CFENCE();                                                            \
        __builtin_amdgcn_s_barrier();                                        \
        CFENCE();                                                            \
        if ((KTI) + 2 < KT) stageW(((KTI) + 2) * 32, (BUF));                 \
    }

    for (int kt = 0; kt < KT; kt += 2) {
        GSTEP(kt, arA, 0)
        GSTEP(kt + 1, arB, 1)
    }
    #undef GSTEP
}

// acc element (n,rt,e) <-> A-row wr*64 + rt*16 + (lane&15),
//                          W-row wc*128 + n*16 + (lane>>4)*4 + e.

// transpose swizzle: X(c) = (((c>>2)&3)<<4) ^ ((c&3)<<3)
__device__ __forceinline__ int tswz(int c) {
    return (((c >> 2) & 3) << 4) ^ ((c & 3) << 3);
}

// smem: 64KB W double-buffer + 6KB epilogue scratch (reductions)
#define SMEM_DECL __shared__ char smem[65536 + 6144]
#define SW ((u16*)smem)
#define EPI (smem + 65536)

// ---------------- fc0 + LN + ReLU ----------------
__launch_bounds__(512, 2)
__global__ void k_fc(const u16* __restrict__ xb, const u16* __restrict__ wb,
                     const float* __restrict__ bias, const float* __restrict__ lg,
                     const float* __restrict__ lb, u16* __restrict__ h) {
    SMEM_DECL;
    float (*redA)[4] = (float(*)[4])EPI;               // [128][4]
    float (*redB)[4] = (float(*)[4])(EPI + 2048);      // [128][4]
    float* mu_s = (float*)(EPI + 4096);                // [128]
    float* rs_s = (float*)(EPI + 4608);                // [128]
    const int t = threadIdx.x, lane = t & 63, w = t >> 6;
    const int q = lane >> 4, m15 = lane & 15;
    const int wr = w >> 2, wc = w & 3;
    const int bx = (int)blockIdx.x;
    const int swz = (bx & 7) * ((int)gridDim.x >> 3) + (bx >> 3);
    const int r0 = swz * 128;
    v4f acc[8][4];
    gemm_core<INCH, INCH>(xb + (size_t)r0 * INCH, wb, SW, acc);

    float sm[4] = {0.f, 0.f, 0.f, 0.f}, sq[4] = {0.f, 0.f, 0.f, 0.f};
    #pragma unroll
    for (int n = 0; n < 8; ++n) {
        int c = wc * 128 + n * 16 + q * 4;
        float4 bi = *(const float4*)(bias + c);
        const float* bp = &bi.x;
        #pragma unroll
        for (int rt = 0; rt < 4; ++rt)
            #pragma unroll
            for (int e = 0; e < 4; ++e) {
                float a = acc[n][rt][e] + bp[e];
                acc[n][rt][e] = a;
                sm[rt] += a; sq[rt] += a * a;
            }
    }
    #pragma unroll
    for (int rt = 0; rt < 4; ++rt) {
        sm[rt] += __shfl_xor(sm[rt], 16); sm[rt] += __shfl_xor(sm[rt], 32);
        sq[rt] += __shfl_xor(sq[rt], 16); sq[rt] += __shfl_xor(sq[rt], 32);
    }
    if (lane < 16)
        #pragma unroll
        for (int rt = 0; rt < 4; ++rt) {
            redA[wr * 64 + rt * 16 + m15][wc] = sm[rt];
            redB[wr * 64 + rt * 16 + m15][wc] = sq[rt];
        }
    __syncthreads();
    if (t < 128) {
        float tt = redA[t][0] + redA[t][1] + redA[t][2] + redA[t][3];
        float t2 = redB[t][0] + redB[t][1] + redB[t][2] + redB[t][3];
        float mu = tt * (1.f / HID);
        float rs = rsqrtf(t2 * (1.f / HID) - mu * mu + 1e-5f);
        mu_s[t] = mu; rs_s[t] = rs;
    }
    __syncthreads();
    #pragma unroll
    for (int n = 0; n < 8; ++n) {
        int c = wc * 128 + n * 16 + q * 4;
        float4 g4 = *(const float4*)(lg + c);
        float4 b4 = *(const float4*)(lb + c);
        #pragma unroll
        for (int rt = 0; rt < 4; ++rt) {
            int row = wr * 64 + rt * 16 + m15;
            float mu = mu_s[row], rs = rs_s[row];
            float v0 = (acc[n][rt][0] - mu) * rs * g4.x + b4.x;
            float v1 = (acc[n][rt][1] - mu) * rs * g4.y + b4.y;
            float v2 = (acc[n][rt][2] - mu) * rs * g4.z + b4.z;
            float v3 = (acc[n][rt][3] - mu) * rs * g4.w + b4.w;
            v0 = v0 > 0.f ? v0 : 0.f; v1 = v1 > 0.f ? v1 : 0.f;
            v2 = v2 > 0.f ? v2 : 0.f; v3 = v3 > 0.f ? v3 : 0.f;
            *(uint2*)&h[(size_t)(r0 + row) * HID + c] = pk4(v0, v1, v2, v3);
        }
    }
}

// ---------------- k/v projection + transposed outputs ----------------
// y==0: k -> eps + L2 row-normalize -> Kt[g][m][l] bf16, fused ks partials.
// y==1: v -> Vt[g][d][l] bf16 only (attn2 reads Vt).
// Transpose via the 64 KB sW region, two 64-row passes (pass == wr).
__launch_bounds__(512, 2)
__global__ void k_proj(const u16* __restrict__ hsrc, const u16* __restrict__ wkb,
                       const u16* __restrict__ wvb, u16* __restrict__ kt,
                       u16* __restrict__ vt, float* __restrict__ ksum) {
    SMEM_DECL;
    float (*red)[4] = (float(*)[4])EPI;                // [128][4]
    float* rowv = (float*)(EPI + 2048);                // [128]
    u16* sT = SW;                                      // 512 ch x 64 rows
    const int t = threadIdx.x, lane = t & 63, w = t >> 6;
    const int q = lane >> 4, m15 = lane & 15;
    const int wr = w >> 2, wc = w & 3;
    const int bx = (int)blockIdx.x;
    const int swz = (bx & 7) * ((int)gridDim.x >> 3) + (bx >> 3);
    const int r0 = swz * 128;
    const int g = swz >> 5;                   // 32 blocks per graph
    const int lbase = (swz & 31) * 128;
    const int mode = blockIdx.y;
    v4f acc[8][4];
    gemm_core<HID, HID>(hsrc + (size_t)r0 * HID, mode ? wvb : wkb, SW, acc);

    const int ch = t;
    const int xs = (((ch >> 2) & 3) << 1) ^ (ch & 3);   // tswz(ch)>>3
    if (mode == 0) {
        float sq[4] = {0.f, 0.f, 0.f, 0.f};
        #pragma unroll
        for (int n = 0; n < 8; ++n)
            #pragma unroll
            for (int rt = 0; rt < 4; ++rt)
                #pragma unroll
                for (int e = 0; e < 4; ++e) {
                    float vv = acc[n][rt][e];
                    if (vv == 0.f) vv = 1e-6f;
                    acc[n][rt][e] = vv;
                    sq[rt] += vv * vv;
                }
        #pragma unroll
        for (int rt = 0; rt < 4; ++rt) {
            sq[rt] += __shfl_xor(sq[rt], 16); sq[rt] += __shfl_xor(sq[rt], 32);
        }
        if (lane < 16)
            #pragma unroll
            for (int rt = 0; rt < 4; ++rt)
                red[wr * 64 + rt * 16 + m15][wc] = sq[rt];
        __syncthreads();
        if (t < 128)
            rowv[t] = rsqrtf(red[t][0] + red[t][1] + red[t][2] + red[t][3]);
        __syncthreads();
        float sum = 0.f;
        #pragma unroll
        for (int pass = 0; pass < 2; ++pass) {
            if (wr == pass) {
                #pragma unroll
                for (int n = 0; n < 8; ++n)
                    #pragma unroll
                    for (int rt = 0; rt < 4; ++rt) {
                        int rl = rt * 16 + m15;           // row within pass
                        float rn = rowv[wr * 64 + rl];
                        #pragma unroll
                        for (int e = 0; e < 4; ++e) {
                            int c = wc * 128 + n * 16 + q * 4 + e;
                            sT[(c << 6) + (rl ^ tswz(c))] = f2bf(acc[n][rt][e] * rn);
                        }
                    }
            }
            __syncthreads();
            u16* op = kt + ((size_t)(g * 512 + ch)) * NNODE + lbase + pass * 64;
            #pragma unroll
            for (int jj = 0; jj < 8; ++jj) {
                v8s cvec = *(const v8s*)&sT[(ch << 6) + jj * 8];
                int l0 = (jj ^ xs) * 8;
                *(v8s*)(op + l0) = cvec;
                const u16* cp = (const u16*)&cvec;
                #pragma unroll
                for (int i = 0; i < 8; ++i) sum += bf2f(cp[i]);
            }
            __syncthreads();
        }
        atomicAdd(&ksum[g * 512 + ch], sum);
    } else {
        #pragma unroll
        for (int pass = 0; pass < 2; ++pass) {
            if (wr == pass) {
                #pragma unroll
                for (int n = 0; n < 8; ++n)
                    #pragma unroll
                    for (int rt = 0; rt < 4; ++rt) {
                        int rl = rt * 16 + m15;
                        #pragma unroll
                        for (int e = 0; e < 4; ++e) {
                            int c = wc * 128 + n * 16 + q * 4 + e;
                            sT[(c << 6) + (rl ^ tswz(c))] = f2bf(acc[n][rt][e]);
                        }
                    }
            }
            __syncthreads();
            u16* op = vt + ((size_t)(g * 512 + ch)) * NNODE + lbase + pass * 64;
            #pragma unroll
            for (int jj = 0; jj < 8; ++jj) {
                v8s cvec = *(const v8s*)&sT[(ch << 6) + jj * 8];
                int l0 = (jj ^ xs) * 8;
                *(v8s*)(op + l0) = cvec;
            }
            __syncthreads();
        }
    }
}

// ---------------- kvsT partial[s][d][m] = sum_{l in split s} Vt[d][l]*Kt[m][l]
// grid: 256 blocks = 4 d-blocks x 4 l-splits x 16 graphs, chunked XCD swizzle.
__launch_bounds__(512, 2)
__global__ void k_kvmm2(const u16* __restrict__ kt, const u16* __restrict__ vt,
                        u16* __restrict__ kvp) {
    SMEM_DECL;
    const int t = threadIdx.x, lane = t & 63, w = t >> 6;
    const int q = lane >> 4, m15 = lane & 15;
    const int wr = w >> 2, wc = w & 3;
    const int bx = (int)blockIdx.x;
    const int swz = (bx & 7) * 32 + (bx >> 3);   // 256 blocks, 32/XCD chunk
    const int db = swz & 3, s = (swz >> 2) & 3, g = swz >> 4;
    const u16* A = vt + ((size_t)(g * 512 + db * 128)) * NNODE + s * 1024;
    const u16* W = kt + ((size_t)(g * 512)) * NNODE + s * 1024;
    v4f acc[8][4];
    gemm_core<NNODE, 1024>(A, W, SW, acc);
    u16* plane = kvp + (size_t)s * NGRAPH * HID * HID;
    #pragma unroll
    for (int n = 0; n < 8; ++n) {
        int m = wc * 128 + n * 16 + q * 4;
        #pragma unroll
        for (int rt = 0; rt < 4; ++rt) {
            int d = db * 128 + wr * 64 + rt * 16 + m15;
            *(uint2*)&plane[((size_t)(g * 512) + d) * 512 + m] =
                pk4(acc[n][rt][0], acc[n][rt][1], acc[n][rt][2], acc[n][rt][3]);
        }
    }
}

// ---------------- q projection + normalize + denom ----------------
__launch_bounds__(512, 2)
__global__ void k_qnorm(const u16* __restrict__ hsrc, const u16* __restrict__ qwb,
                        const float* __restrict__ ks, u16* __restrict__ qo,
                        float* __restrict__ dnv) {
    SMEM_DECL;
    float (*redA)[4] = (float(*)[4])EPI;               // ss
    float (*redB)[4] = (float(*)[4])(EPI + 2048);      // ws
    float* rowv = (float*)(EPI + 4096);                // rn
    const int t = threadIdx.x, lane = t & 63, w = t >> 6;
    const int q = lane >> 4, m15 = lane & 15;
    const int wr = w >> 2, wc = w & 3;
    const int bx = (int)blockIdx.x;
    const int swz = (bx & 7) * ((int)gridDim.x >> 3) + (bx >> 3);
    const int r0 = swz * 128;
    const int gi = swz >> 5;            // 32 blocks per graph
    v4f acc[8][4];
    gemm_core<HID, HID>(hsrc + (size_t)r0 * HID, qwb, SW, acc);

    float ss[4] = {0.f, 0.f, 0.f, 0.f}, ws[4] = {0.f, 0.f, 0.f, 0.f};
    #pragma unroll
    for (int n = 0; n < 8; ++n) {
        int c = wc * 128 + n * 16 + q * 4;
        float4 kv = *(const float4*)(ks + (gi << 9) + c);
        const float* kp = &kv.x;
        #pragma unroll
        for (int rt = 0; rt < 4; ++rt)
            #pragma unroll
            for (int e = 0; e < 4; ++e) {
                float vv = acc[n][rt][e];
                if (vv == 0.f) vv = 1e-6f;
                acc[n][rt][e] = vv;
                ss[rt] += vv * vv; ws[rt] += vv * kp[e];
            }
    }
    #pragma unroll
    for (int rt = 0; rt < 4; ++rt) {
        ss[rt] += __shfl_xor(ss[rt], 16); ss[rt] += __shfl_xor(ss[rt], 32);
        ws[rt] += __shfl_xor(ws[rt], 16); ws[rt] += __shfl_xor(ws[rt], 32);
    }
    if (lane < 16)
        #pragma unroll
        for (int rt = 0; rt < 4; ++rt) {
            redA[wr * 64 + rt * 16 + m15][wc] = ss[rt];
            redB[wr * 64 + rt * 16 + m15][wc] = ws[rt];
        }
    __syncthreads();
    if (t < 128) {
        float st = redA[t][0] + redA[t][1] + redA[t][2] + redA[t][3];
        float wt = redB[t][0] + redB[t][1] + redB[t][2] + redB[t][3];
        float rn = rsqrtf(st);
        rowv[t] = rn;
        dnv[r0 + t] = 1.f / (rn * wt + (float)NNODE);
    }
    __syncthreads();
    #pragma unroll
    for (int n = 0; n < 8; ++n) {
        int c = wc * 128 + n * 16 + q * 4;
        #pragma unroll
        for (int rt = 0; rt < 4; ++rt) {
            int row = wr * 64 + rt * 16 + m15;
            float rn = rowv[row];
            *(uint2*)&qo[(size_t)(r0 + row) * HID + c] =
                pk4(acc[n][rt][0] * rn, acc[n][rt][1] * rn,
                    acc[n][rt][2] * rn, acc[n][rt][3] * rn);
        }
    }
}

// ---------------- num = qhat @ kvsT^T + residual + LN + ReLU ----------------
// v from transposed bf16 Vt (scalar u16 loads, 16-lane-contiguous segments).
__launch_bounds__(512, 2)
__global__ void k_attn2(const u16* __restrict__ qhat, const u16* __restrict__ kvstb,
                        const float* __restrict__ dnv, const u16* __restrict__ vt,
                        const u16* __restrict__ hsrc, const float* __restrict__ lg,
                        const float* __restrict__ lb, u16* __restrict__ outb,
                        float* __restrict__ outf) {
    SMEM_DECL;
    float (*redA)[4] = (float(*)[4])EPI;
    float (*redB)[4] = (float(*)[4])(EPI + 2048);
    float* mu_s = (float*)(EPI + 4096);
    float* rs_s = (float*)(EPI + 4608);
    const int t = threadIdx.x, lane = t & 63, w = t >> 6;
    const int q = lane >> 4, m15 = lane & 15;
    const int wr = w >> 2, wc = w & 3;
    const int bx = (int)blockIdx.x;
    const int swz = (bx & 7) * ((int)gridDim.x >> 3) + (bx >> 3);
    const int r0 = swz * 128;
    const int gi = swz >> 5;
    v4f acc[8][4];
    gemm_core<HID, HID>(qhat + (size_t)r0 * HID, kvstb + (size_t)gi * HID * HID,
                        SW, acc);

    float dv[4];
    #pragma unroll
    for (int rt = 0; rt < 4; ++rt) dv[rt] = dnv[r0 + wr * 64 + rt * 16 + m15];
    const u16* vtg = vt + (size_t)(gi * 512) * NNODE + ((swz & 31) * 128 + wr * 64 + m15);
    float sm[4] = {0.f, 0.f, 0.f, 0.f}, sq[4] = {0.f, 0.f, 0.f, 0.f};
    #pragma unroll
    for (int n = 0; n < 8; ++n) {
        int c = wc * 128 + n * 16 + q * 4;
        const u16* vb = vtg + (size_t)c * NNODE;
        #pragma unroll
        for (int rt = 0; rt < 4; ++rt) {
            int row = wr * 64 + rt * 16 + m15;
            size_t og = (size_t)(r0 + row) * HID + c;
            float hh[4]; up4(*(const uint2*)&hsrc[og], hh);
            #pragma unroll
            for (int e = 0; e < 4; ++e) {
                float vv = bf2f(vb[(size_t)e * NNODE + rt * 16]);
                float a = ((acc[n][rt][e] + (float)NNODE * vv) * dv[rt] + hh[e]) * 0.5f;
                acc[n][rt][e] = a;
                sm[rt] += a; sq[rt] += a * a;
            }
        }
    }
    #pragma unroll
    for (int rt = 0; rt < 4; ++rt) {
        sm[rt] += __shfl_xor(sm[rt], 16); sm[rt] += __shfl_xor(sm[rt], 32);
        sq[rt] += __shfl_xor(sq[rt], 16); sq[rt] += __shfl_xor(sq[rt], 32);
    }
    if (lane < 16)
        #pragma unroll
        for (int rt = 0; rt < 4; ++rt) {
            redA[wr * 64 + rt * 16 + m15][wc] = sm[rt];
            redB[wr * 64 + rt * 16 + m15][wc] = sq[rt];
        }
    __syncthreads();
    if (t < 128) {
        float tt = redA[t][0] + redA[t][1] + redA[t][2] + redA[t][3];
        float t2 = redB[t][0] + redB[t][1] + redB[t][2] + redB[t][3];
        float mu = tt * (1.f / HID);
        float rs = rsqrtf(t2 * (1.f / HID) - mu * mu + 1e-5f);
        mu_s[t] = mu; rs_s[t] = rs;
    }
    __syncthreads();
    #pragma unroll
    for (int n = 0; n < 8; ++n) {
        int c = wc * 128 + n * 16 + q * 4;
        float4 g4 = *(const float4*)(lg + c);
        float4 b4 = *(const float4*)(lb + c);
        #pragma unroll
        for (int rt = 0; rt < 4; ++rt) {
            int row = wr * 64 + rt * 16 + m15;
            float mu = mu_s[row], rs = rs_s[row];
            float v0 = (acc[n][rt][0] - mu) * rs * g4.x + b4.x;
            float v1 = (acc[n][rt][1] - mu) * rs * g4.y + b4.y;
            float v2 = (acc[n][rt][2] - mu) * rs * g4.z + b4.z;
            float v3 = (acc[n][rt][3] - mu) * rs * g4.w + b4.w;
            v0 = v0 > 0.f ? v0 : 0.f; v1 = v1 > 0.f ? v1 : 0.f;
            v2 = v2 > 0.f ? v2 : 0.f; v3 = v3 > 0.f ? v3 : 0.f;
            size_t og = (size_t)(r0 + row) * HID + c;
            if (outf) {
                float4 o = {v0, v1, v2, v3};
                *(float4*)&outf[og] = o;
            } else {
                *(uint2*)&outb[og] = pk4(v0, v1, v2, v3);
            }
        }
    }
}

extern "C" void kernel_launch(void* const* d_in, const int* in_sizes, int n_in,
                              void* d_out, int out_size, void* d_ws, size_t ws_size,
                              hipStream_t stream) {
    const float* x    = (const float*)d_in[0];
    const float* fc0w = (const float*)d_in[1];
    const float* fc0b = (const float*)d_in[2];
    const float* ln0g = (const float*)d_in[3];
    const float* ln0b = (const float*)d_in[4];
    const float* q0w  = (const float*)d_in[5];
    const float* k0w  = (const float*)d_in[6];
    const float* v0w  = (const float*)d_in[7];
    const float* ln1g = (const float*)d_in[8];
    const float* ln1b = (const float*)d_in[9];
    const float* q1w  = (const float*)d_in[10];
    const float* k1w  = (const float*)d_in[11];
    const float* v1w  = (const float*)d_in[12];
    const float* ln2g = (const float*)d_in[13];
    const float* ln2b = (const float*)d_in[14];
    // batch (d_in[15]) = repeat(arange(16),4096): argsort == identity. unused.

    // workspace (~247 MB):
    //   H(64M) | Kt(64M, then qhat) | Vt(64M, Xb first) | KVp x4(33.5M) |
    //   KVb(8.4M) | KS | DNV | weights bf16(3.4M)
    const size_t M64 = (size_t)TNODES * HID * 2;          // 64 MiB
    const size_t PL  = (size_t)NGRAPH * HID * HID * 2;    // 8.39 MB plane
    char* wsc = (char*)d_ws;
    u16*   H   = (u16*)wsc;
    u16*   Kt  = (u16*)(wsc + M64);
    u16*   Vt  = (u16*)(wsc + 2 * M64);
    u16*   KVp = (u16*)(wsc + 3 * M64);
    u16*   KVb = (u16*)(wsc + 3 * M64 + 4 * PL);
    float* KS  = (float*)(wsc + 3 * M64 + 5 * PL);
    float* DNV = KS + NGRAPH * HID;
    u16*   Wc  = (u16*)((char*)DNV + (size_t)TNODES * sizeof(float));
    u16* fc0wb = Wc;
    u16* q0b = Wc + 131072;
    u16* k0b = Wc + 393216;
    u16* v0b = Wc + 655360;
    u16* q1b = Wc + 917504;
    u16* k1b = Wc + 1179648;
    u16* v1b = Wc + 1441792;
    u16* Xb  = Vt;                 // consumed by k_fc before layer-1 proj writes Vt
    u16* QH  = Kt;                 // qhat overwrites Kt after kvmm2 consumed it
                                   // (Vt stays live for attn2's v reads)

    dim3 b256(256), b512(512);
    k_cvt4<<<dim3(64),  b256, 0, stream>>>(fc0w, fc0wb, HID * INCH / 4);
    k_cvt4<<<dim3(64),  b256, 0, stream>>>(q0w, q0b, HID * HID / 4);
    k_cvt4<<<dim3(64),  b256, 0, stream>>>(k0w, k0b, HID * HID / 4);
    k_cvt4<<<dim3(64),  b256, 0, stream>>>(v0w, v0b, HID * HID / 4);
    k_cvt4<<<dim3(64),  b256, 0, stream>>>(q1w, q1b, HID * HID / 4);
    k_cvt4<<<dim3(64),  b256, 0, stream>>>(k1w, k1b, HID * HID / 4);
    k_cvt4<<<dim3(64),  b256, 0, stream>>>(v1w, v1b, HID * HID / 4);
    k_cvt4<<<dim3(1024), b256, 0, stream>>>(x, Xb, TNODES * INCH / 4);

    k_fc<<<dim3(TNODES / 128), b512, 0, stream>>>(Xb, fc0wb, fc0b, ln0g, ln0b, H);

    // ---- layer 1 ----
    k_zero<<<dim3(32), b256, 0, stream>>>(KS, NGRAPH * HID);
    k_proj<<<dim3(TNODES / 128, 2), b512, 0, stream>>>(H, k0b, v0b, Kt, Vt, KS);
    k_kvmm2<<<dim3(256), b512, 0, stream>>>(Kt, Vt, KVp);
    k_red4<<<dim3(2048), b256, 0, stream>>>(KVp, KVb, NGRAPH * HID * HID / 8);
    k_qnorm<<<dim3(TNODES / 128), b512, 0, stream>>>(H, q0b, KS, QH, DNV);
    k_attn2<<<dim3(TNODES / 128), b512, 0, stream>>>(QH, KVb, DNV, Vt, H, ln1g, ln1b,
                                                     H, nullptr);   // H := layer-1 out

    // ---- layer 2 ----
    k_zero<<<dim3(32), b256, 0, stream>>>(KS, NGRAPH * HID);
    k_proj<<<dim3(TNODES / 128, 2), b512, 0, stream>>>(H, k1b, v1b, Kt, Vt, KS);
    k_kvmm2<<<dim3(256), b512, 0, stream>>>(Kt, Vt, KVp);
    k_red4<<<dim3(2048), b256, 0, stream>>>(KVp, KVb, NGRAPH * HID * HID / 8);
    k_qnorm<<<dim3(TNODES / 128), b512, 0, stream>>>(H, q1b, KS, QH, DNV);
    k_attn2<<<dim3(TNODES / 128), b512, 0, stream>>>(QH, KVb, DNV, Vt, H, ln2g, ln2b,
                                                     nullptr, (float*)d_out);
}

// Round 8
// 1016.567 us; speedup vs baseline: 1.0626x; 1.0626x over previous
//
#include <hip/hip_runtime.h>

#define TNODES 65536
#define NGRAPH 16
#define NNODE  4096
#define INCH   256
#define HID    512

using u16 = unsigned short;
using u32 = unsigned int;
using v8s = __attribute__((ext_vector_type(8))) short;   // 8 bf16 (4 VGPRs)
using v4f = __attribute__((ext_vector_type(4))) float;   // 4 fp32 acc

__device__ __forceinline__ float bf2f(u16 u) {
    union { u32 i; float f; } v; v.i = ((u32)u) << 16; return v.f;
}
__device__ __forceinline__ u16 f2bf(float f) {
    union { float f; u32 i; } v; v.f = f;
    u32 x = v.i;
    return (u16)((x + 0x7fffu + ((x >> 16) & 1u)) >> 16);
}
__device__ __forceinline__ void up4(uint2 p, float* f) {
    f[0] = __uint_as_float(p.x << 16); f[1] = __uint_as_float(p.x & 0xffff0000u);
    f[2] = __uint_as_float(p.y << 16); f[3] = __uint_as_float(p.y & 0xffff0000u);
}
__device__ __forceinline__ uint2 pk4(float a, float b, float c, float d) {
    uint2 r;
    r.x = (u32)f2bf(a) | ((u32)f2bf(b) << 16);
    r.y = (u32)f2bf(c) | ((u32)f2bf(d) << 16);
    return r;
}

#define MFMA(a, b, c) __builtin_amdgcn_mfma_f32_16x16x32_bf16((a), (b), (c), 0, 0, 0)

// async global->LDS, 16B per lane. dest = wave-uniform base + lane*16 (linear).
#define GLD16(gp, sp) __builtin_amdgcn_global_load_lds( \
    (const __attribute__((address_space(1))) u32*)(const void*)(gp), \
    (__attribute__((address_space(3))) u32*)(void*)(sp), 16, 0, 0)

#define CFENCE() asm volatile("" ::: "memory")

// ---------------- fp32 -> bf16 convert, vectorized ----------------
__global__ void k_cvt4(const float* __restrict__ s, u16* __restrict__ d, int n4) {
    for (int i = blockIdx.x * blockDim.x + threadIdx.x; i < n4; i += gridDim.x * blockDim.x) {
        float4 f = ((const float4*)s)[i];
        ((uint2*)d)[i] = pk4(f.x, f.y, f.z, f.w);
    }
}

__global__ void k_zero(float* __restrict__ p, int n) {
    int i = blockIdx.x * 256 + threadIdx.x;
    if (i < n) p[i] = 0.f;
}

// ---------------- sum 4 bf16 partial planes -> bf16 ----------------
__global__ void k_red4(const u16* __restrict__ p, u16* __restrict__ o, int n8) {
    const size_t P = (size_t)NGRAPH * HID * HID;
    for (int i = blockIdx.x * blockDim.x + threadIdx.x; i < n8; i += gridDim.x * blockDim.x) {
        size_t b = (size_t)i * 8;
        float s[8] = {0.f, 0.f, 0.f, 0.f, 0.f, 0.f, 0.f, 0.f};
        #pragma unroll
        for (int ss = 0; ss < 4; ++ss) {
            v8s v = *(const v8s*)(p + ss * P + b);
            const u16* vp = (const u16*)&v;
            #pragma unroll
            for (int j = 0; j < 8; ++j) s[j] += bf2f(vp[j]);
        }
        uint2 lo = pk4(s[0], s[1], s[2], s[3]);
        uint2 hi = pk4(s[4], s[5], s[6], s[7]);
        uint4 w; w.x = lo.x; w.y = lo.y; w.z = hi.x; w.w = hi.y;
        *(uint4*)(o + b) = w;
    }
}

// =====================================================================
// GEMM core (round-6 version, best measured): C[128 x 512] =
// Act[128 rows, stride LDK] @ W[512 rows]^T. 512 threads = 8 waves
// (2 row-groups x 4 col-groups), wave tile 64x128 (acc[8][4]). BK=32,
// A and W both double-buffered in LDS via global_load_lds(16B) (2-step
// prefetch distance -- r7 showed per-lane A reg-loads with 1-step
// distance regress 21%). XOR-swizzle on global source + same on ds_read.
// Counted vmcnt(5): 5 loads/thread/stage stay in flight across barriers.
// =====================================================================
template<int LDK, int KLEN>
__device__ __forceinline__ void gemm_core(const u16* __restrict__ A,
                                          const u16* __restrict__ W,
                                          u16* sA, u16* sW, v4f (&acc)[8][4]) {
    const int t = threadIdx.x, lane = t & 63;
    const int q = lane >> 4, m15 = lane & 15;
    const int w = t >> 6, wr = w >> 2, wc = w & 3;

    #pragma unroll
    for (int n = 0; n < 8; ++n)
        #pragma unroll
        for (int rt = 0; rt < 4; ++rt)
            #pragma unroll
            for (int e = 0; e < 4; ++e) acc[n][rt][e] = 0.f;

    int aoff[4], woff[8];
    #pragma unroll
    for (int rt = 0; rt < 4; ++rt) {
        int r = wr * 64 + rt * 16 + m15;
        aoff[rt] = r * 32 + ((q ^ ((r >> 1) & 3)) * 8);
    }
    #pragma unroll
    for (int n = 0; n < 8; ++n) {
        int r = wc * 128 + n * 16 + m15;
        woff[n] = r * 32 + ((q ^ ((r >> 1) & 3)) * 8);
    }

    auto stage = [&](int k0, int buf) {
        u16* dW = sW + buf * (512 * 32);
        #pragma unroll
        for (int p = 0; p < 4; ++p) {
            int sf = p * 512 + t, row = sf >> 2, sl = sf & 3;
            int gc = k0 + ((sl ^ ((row >> 1) & 3)) * 8);
            GLD16(W + (size_t)row * LDK + gc, dW + sf * 8);
        }
        {   // A-tile: 128 rows x 32, one 16B load per thread
            int row = t >> 2, sl = t & 3;
            int gc = k0 + ((sl ^ ((row >> 1) & 3)) * 8);
            GLD16(A + (size_t)row * LDK + gc, sA + buf * (128 * 32) + t * 8);
        }
    };

    const int KT = KLEN / 32;
    stage(0, 0);
    stage(32, 1);
    int cur = 0;
    for (int kt = 0; kt < KT; ++kt) {
        if (kt + 1 < KT) asm volatile("s_waitcnt vmcnt(5)" ::: "memory");
        else             asm volatile("s_waitcnt vmcnt(0)" ::: "memory");
        __builtin_amdgcn_s_barrier();
        CFENCE();
        __builtin_amdgcn_sched_barrier(0);
        const u16* cA = sA + cur * (128 * 32);
        const u16* cW = sW + cur * (512 * 32);
        v8s b[4];
        #pragma unroll
        for (int rt = 0; rt < 4; ++rt) b[rt] = *(const v8s*)(cA + aoff[rt]);
        #pragma unroll
        for (int n = 0; n < 8; ++n) {
            v8s af = *(const v8s*)(cW + woff[n]);
            #pragma unroll
            for (int rt = 0; rt < 4; ++rt)
                acc[n][rt] = MFMA(af, b[rt], acc[n][rt]);
        }
        CFENCE();
        __builtin_amdgcn_s_barrier();
        CFENCE();
        if (kt + 2 < KT) stage((kt + 2) * 32, cur);
        cur ^= 1;
    }
}

// acc element (n,rt,e) <-> A-row wr*64 + rt*16 + (lane&15),
//                          W-row wc*128 + n*16 + (lane>>4)*4 + e.

// transpose swizzle: X(c) = (((c>>2)&3)<<4) ^ ((c&3)<<3)
__device__ __forceinline__ int tswz(int c) {
    return (((c >> 2) & 3) << 4) ^ ((c & 3) << 3);
}

// smem: 16KB sA dbuf + 64KB sW dbuf = 80KB -> 2 blocks/CU.
// Epilogue scratch aliases the sA region (dead after the GEMM).
#define SMEM_DECL __shared__ char smem[81920]
#define SA ((u16*)smem)
#define SW ((u16*)(smem + 16384))
#define EPI (smem)

// ---------------- fc0 + LN + ReLU ----------------
__launch_bounds__(512, 2)
__global__ void k_fc(const u16* __restrict__ xb, const u16* __restrict__ wb,
                     const float* __restrict__ bias, const float* __restrict__ lg,
                     const float* __restrict__ lb, u16* __restrict__ h) {
    SMEM_DECL;
    float (*redA)[4] = (float(*)[4])EPI;               // [128][4]
    float (*redB)[4] = (float(*)[4])(EPI + 2048);      // [128][4]
    float* mu_s = (float*)(EPI + 4096);                // [128]
    float* rs_s = (float*)(EPI + 4608);                // [128]
    const int t = threadIdx.x, lane = t & 63, w = t >> 6;
    const int q = lane >> 4, m15 = lane & 15;
    const int wr = w >> 2, wc = w & 3;
    const int bx = (int)blockIdx.x;
    const int swz = (bx & 7) * ((int)gridDim.x >> 3) + (bx >> 3);
    const int r0 = swz * 128;
    v4f acc[8][4];
    gemm_core<INCH, INCH>(xb + (size_t)r0 * INCH, wb, SA, SW, acc);

    float sm[4] = {0.f, 0.f, 0.f, 0.f}, sq[4] = {0.f, 0.f, 0.f, 0.f};
    #pragma unroll
    for (int n = 0; n < 8; ++n) {
        int c = wc * 128 + n * 16 + q * 4;
        float4 bi = *(const float4*)(bias + c);
        const float* bp = &bi.x;
        #pragma unroll
        for (int rt = 0; rt < 4; ++rt)
            #pragma unroll
            for (int e = 0; e < 4; ++e) {
                float a = acc[n][rt][e] + bp[e];
                acc[n][rt][e] = a;
                sm[rt] += a; sq[rt] += a * a;
            }
    }
    #pragma unroll
    for (int rt = 0; rt < 4; ++rt) {
        sm[rt] += __shfl_xor(sm[rt], 16); sm[rt] += __shfl_xor(sm[rt], 32);
        sq[rt] += __shfl_xor(sq[rt], 16); sq[rt] += __shfl_xor(sq[rt], 32);
    }
    __syncthreads();   // sA reads done before EPI aliasing writes
    if (lane < 16)
        #pragma unroll
        for (int rt = 0; rt < 4; ++rt) {
            redA[wr * 64 + rt * 16 + m15][wc] = sm[rt];
            redB[wr * 64 + rt * 16 + m15][wc] = sq[rt];
        }
    __syncthreads();
    if (t < 128) {
        float tt = redA[t][0] + redA[t][1] + redA[t][2] + redA[t][3];
        float t2 = redB[t][0] + redB[t][1] + redB[t][2] + redB[t][3];
        float mu = tt * (1.f / HID);
        float rs = rsqrtf(t2 * (1.f / HID) - mu * mu + 1e-5f);
        mu_s[t] = mu; rs_s[t] = rs;
    }
    __syncthreads();
    #pragma unroll
    for (int n = 0; n < 8; ++n) {
        int c = wc * 128 + n * 16 + q * 4;
        float4 g4 = *(const float4*)(lg + c);
        float4 b4 = *(const float4*)(lb + c);
        #pragma unroll
        for (int rt = 0; rt < 4; ++rt) {
            int row = wr * 64 + rt * 16 + m15;
            float mu = mu_s[row], rs = rs_s[row];
            float v0 = (acc[n][rt][0] - mu) * rs * g4.x + b4.x;
            float v1 = (acc[n][rt][1] - mu) * rs * g4.y + b4.y;
            float v2 = (acc[n][rt][2] - mu) * rs * g4.z + b4.z;
            float v3 = (acc[n][rt][3] - mu) * rs * g4.w + b4.w;
            v0 = v0 > 0.f ? v0 : 0.f; v1 = v1 > 0.f ? v1 : 0.f;
            v2 = v2 > 0.f ? v2 : 0.f; v3 = v3 > 0.f ? v3 : 0.f;
            *(uint2*)&h[(size_t)(r0 + row) * HID + c] = pk4(v0, v1, v2, v3);
        }
    }
}

// ---------------- k/v projection + transposed outputs ----------------
// y==0: k -> eps + L2 row-normalize -> Kt[g][m][l] bf16, fused ks partials.
// y==1: v -> V fp32 identity (coalesced, for attn2's epilogue; lives in
//        d_out) AND Vt[g][d][l] bf16 (for kvmm).
// Transpose via the 64 KB sW region, two 64-row passes (pass == wr).
__launch_bounds__(512, 2)
__global__ void k_proj(const u16* __restrict__ hsrc, const u16* __restrict__ wkb,
                       const u16* __restrict__ wvb, u16* __restrict__ kt,
                       u16* __restrict__ vt, float* __restrict__ vo,
                       float* __restrict__ ksum) {
    SMEM_DECL;
    float (*red)[4] = (float(*)[4])EPI;                // [128][4]
    float* rowv = (float*)(EPI + 2048);                // [128]
    u16* sT = SW;                                      // 512 ch x 64 rows
    const int t = threadIdx.x, lane = t & 63, w = t >> 6;
    const int q = lane >> 4, m15 = lane & 15;
    const int wr = w >> 2, wc = w & 3;
    const int bx = (int)blockIdx.x;
    const int swz = (bx & 7) * ((int)gridDim.x >> 3) + (bx >> 3);
    const int r0 = swz * 128;
    const int g = swz >> 5;                   // 32 blocks per graph
    const int lbase = (swz & 31) * 128;
    const int mode = blockIdx.y;
    v4f acc[8][4];
    gemm_core<HID, HID>(hsrc + (size_t)r0 * HID, mode ? wvb : wkb, SA, SW, acc);

    const int ch = t;
    const int xs = (((ch >> 2) & 3) << 1) ^ (ch & 3);   // tswz(ch)>>3
    if (mode == 0) {
        float sq[4] = {0.f, 0.f, 0.f, 0.f};
        #pragma unroll
        for (int n = 0; n < 8; ++n)
            #pragma unroll
            for (int rt = 0; rt < 4; ++rt)
                #pragma unroll
                for (int e = 0; e < 4; ++e) {
                    float vv = acc[n][rt][e];
                    if (vv == 0.f) vv = 1e-6f;
                    acc[n][rt][e] = vv;
                    sq[rt] += vv * vv;
                }
        #pragma unroll
        for (int rt = 0; rt < 4; ++rt) {
            sq[rt] += __shfl_xor(sq[rt], 16); sq[rt] += __shfl_xor(sq[rt], 32);
        }
        __syncthreads();
        if (lane < 16)
            #pragma unroll
            for (int rt = 0; rt < 4; ++rt)
                red[wr * 64 + rt * 16 + m15][wc] = sq[rt];
        __syncthreads();
        if (t < 128)
            rowv[t] = rsqrtf(red[t][0] + red[t][1] + red[t][2] + red[t][3]);
        __syncthreads();
        float sum = 0.f;
        #pragma unroll
        for (int pass = 0; pass < 2; ++pass) {
            if (wr == pass) {
                #pragma unroll
                for (int n = 0; n < 8; ++n)
                    #pragma unroll
                    for (int rt = 0; rt < 4; ++rt) {
                        int rl = rt * 16 + m15;           // row within pass
                        float rn = rowv[wr * 64 + rl];
                        #pragma unroll
                        for (int e = 0; e < 4; ++e) {
                            int c = wc * 128 + n * 16 + q * 4 + e;
                            sT[(c << 6) + (rl ^ tswz(c))] = f2bf(acc[n][rt][e] * rn);
                        }
                    }
            }
            __syncthreads();
            u16* op = kt + ((size_t)(g * 512 + ch)) * NNODE + lbase + pass * 64;
            #pragma unroll
            for (int jj = 0; jj < 8; ++jj) {
                v8s cvec = *(const v8s*)&sT[(ch << 6) + jj * 8];
                int l0 = (jj ^ xs) * 8;
                *(v8s*)(op + l0) = cvec;
                const u16* cp = (const u16*)&cvec;
                #pragma unroll
                for (int i = 0; i < 8; ++i) sum += bf2f(cp[i]);
            }
            __syncthreads();
        }
        atomicAdd(&ksum[g * 512 + ch], sum);
    } else {
        #pragma unroll
        for (int n = 0; n < 8; ++n) {
            int c = wc * 128 + n * 16 + q * 4;
            #pragma unroll
            for (int rt = 0; rt < 4; ++rt) {
                int row = wr * 64 + rt * 16 + m15;
                float4 o = {acc[n][rt][0], acc[n][rt][1], acc[n][rt][2], acc[n][rt][3]};
                *(float4*)&vo[(size_t)(r0 + row) * HID + c] = o;
            }
        }
        __syncthreads();
        #pragma unroll
        for (int pass = 0; pass < 2; ++pass) {
            if (wr == pass) {
                #pragma unroll
                for (int n = 0; n < 8; ++n)
                    #pragma unroll
                    for (int rt = 0; rt < 4; ++rt) {
                        int rl = rt * 16 + m15;
                        #pragma unroll
                        for (int e = 0; e < 4; ++e) {
                            int c = wc * 128 + n * 16 + q * 4 + e;
                            sT[(c << 6) + (rl ^ tswz(c))] = f2bf(acc[n][rt][e]);
                        }
                    }
            }
            __syncthreads();
            u16* op = vt + ((size_t)(g * 512 + ch)) * NNODE + lbase + pass * 64;
            #pragma unroll
            for (int jj = 0; jj < 8; ++jj) {
                v8s cvec = *(const v8s*)&sT[(ch << 6) + jj * 8];
                int l0 = (jj ^ xs) * 8;
                *(v8s*)(op + l0) = cvec;
            }
            __syncthreads();
        }
    }
}

// ---------------- kvsT partial[s][d][m] = sum_{l in split s} Vt[d][l]*Kt[m][l]
// grid: 256 blocks = 4 d-blocks x 4 l-splits x 16 graphs, chunked XCD swizzle.
__launch_bounds__(512, 2)
__global__ void k_kvmm2(const u16* __restrict__ kt, const u16* __restrict__ vt,
                        u16* __restrict__ kvp) {
    SMEM_DECL;
    const int t = threadIdx.x, lane = t & 63, w = t >> 6;
    const int q = lane >> 4, m15 = lane & 15;
    const int wr = w >> 2, wc = w & 3;
    const int bx = (int)blockIdx.x;
    const int swz = (bx & 7) * 32 + (bx >> 3);   // 256 blocks, 32/XCD chunk
    const int db = swz & 3, s = (swz >> 2) & 3, g = swz >> 4;
    const u16* A = vt + ((size_t)(g * 512 + db * 128)) * NNODE + s * 1024;
    const u16* W = kt + ((size_t)(g * 512)) * NNODE + s * 1024;
    v4f acc[8][4];
    gemm_core<NNODE, 1024>(A, W, SA, SW, acc);
    u16* plane = kvp + (size_t)s * NGRAPH * HID * HID;
    #pragma unroll
    for (int n = 0; n < 8; ++n) {
        int m = wc * 128 + n * 16 + q * 4;
        #pragma unroll
        for (int rt = 0; rt < 4; ++rt) {
            int d = db * 128 + wr * 64 + rt * 16 + m15;
            *(uint2*)&plane[((size_t)(g * 512) + d) * 512 + m] =
                pk4(acc[n][rt][0], acc[n][rt][1], acc[n][rt][2], acc[n][rt][3]);
        }
    }
}

// ---------------- q projection + normalize + denom ----------------
__launch_bounds__(512, 2)
__global__ void k_qnorm(const u16* __restrict__ hsrc, const u16* __restrict__ qwb,
                        const float* __restrict__ ks, u16* __restrict__ qo,
                        float* __restrict__ dnv) {
    SMEM_DECL;
    float (*redA)[4] = (float(*)[4])EPI;               // ss
    float (*redB)[4] = (float(*)[4])(EPI + 2048);      // ws
    float* rowv = (float*)(EPI + 4096);                // rn
    const int t = threadIdx.x, lane = t & 63, w = t >> 6;
    const int q = lane >> 4, m15 = lane & 15;
    const int wr = w >> 2, wc = w & 3;
    const int bx = (int)blockIdx.x;
    const int swz = (bx & 7) * ((int)gridDim.x >> 3) + (bx >> 3);
    const int r0 = swz * 128;
    const int gi = swz >> 5;            // 32 blocks per graph
    v4f acc[8][4];
    gemm_core<HID, HID>(hsrc + (size_t)r0 * HID, qwb, SA, SW, acc);

    float ss[4] = {0.f, 0.f, 0.f, 0.f}, ws[4] = {0.f, 0.f, 0.f, 0.f};
    #pragma unroll
    for (int n = 0; n < 8; ++n) {
        int c = wc * 128 + n * 16 + q * 4;
        float4 kv = *(const float4*)(ks + (gi << 9) + c);
        const float* kp = &kv.x;
        #pragma unroll
        for (int rt = 0; rt < 4; ++rt)
            #pragma unroll
            for (int e = 0; e < 4; ++e) {
                float vv = acc[n][rt][e];
                if (vv == 0.f) vv = 1e-6f;
                acc[n][rt][e] = vv;
                ss[rt] += vv * vv; ws[rt] += vv * kp[e];
            }
    }
    #pragma unroll
    for (int rt = 0; rt < 4; ++rt) {
        ss[rt] += __shfl_xor(ss[rt], 16); ss[rt] += __shfl_xor(ss[rt], 32);
        ws[rt] += __shfl_xor(ws[rt], 16); ws[rt] += __shfl_xor(ws[rt], 32);
    }
    __syncthreads();
    if (lane < 16)
        #pragma unroll
        for (int rt = 0; rt < 4; ++rt) {
            redA[wr * 64 + rt * 16 + m15][wc] = ss[rt];
            redB[wr * 64 + rt * 16 + m15][wc] = ws[rt];
        }
    __syncthreads();
    if (t < 128) {
        float st = redA[t][0] + redA[t][1] + redA[t][2] + redA[t][3];
        float wt = redB[t][0] + redB[t][1] + redB[t][2] + redB[t][3];
        float rn = rsqrtf(st);
        rowv[t] = rn;
        dnv[r0 + t] = 1.f / (rn * wt + (float)NNODE);
    }
    __syncthreads();
    #pragma unroll
    for (int n = 0; n < 8; ++n) {
        int c = wc * 128 + n * 16 + q * 4;
        #pragma unroll
        for (int rt = 0; rt < 4; ++rt) {
            int row = wr * 64 + rt * 16 + m15;
            float rn = rowv[row];
            *(uint2*)&qo[(size_t)(r0 + row) * HID + c] =
                pk4(acc[n][rt][0] * rn, acc[n][rt][1] * rn,
                    acc[n][rt][2] * rn, acc[n][rt][3] * rn);
        }
    }
}

// ---------------- num = qhat @ kvsT^T + residual + LN + ReLU ----------------
// v read as coalesced fp32 (identity layout in d_out; same rows are written
// at the end -> in-place safe within the block).
__launch_bounds__(512, 2)
__global__ void k_attn2(const u16* __restrict__ qhat, const u16* __restrict__ kvstb,
                        const float* __restrict__ dnv, const float* __restrict__ vsrc,
                        const u16* __restrict__ hsrc, const float* __restrict__ lg,
                        const float* __restrict__ lb, u16* __restrict__ outb,
                        float* __restrict__ outf) {
    SMEM_DECL;
    float (*redA)[4] = (float(*)[4])EPI;
    float (*redB)[4] = (float(*)[4])(EPI + 2048);
    float* mu_s = (float*)(EPI + 4096);
    float* rs_s = (float*)(EPI + 4608);
    const int t = threadIdx.x, lane = t & 63, w = t >> 6;
    const int q = lane >> 4, m15 = lane & 15;
    const int wr = w >> 2, wc = w & 3;
    const int bx = (int)blockIdx.x;
    const int swz = (bx & 7) * ((int)gridDim.x >> 3) + (bx >> 3);
    const int r0 = swz * 128;
    const int gi = swz >> 5;
    v4f acc[8][4];
    gemm_core<HID, HID>(qhat + (size_t)r0 * HID, kvstb + (size_t)gi * HID * HID,
                        SA, SW, acc);

    float dv[4];
    #pragma unroll
    for (int rt = 0; rt < 4; ++rt) dv[rt] = dnv[r0 + wr * 64 + rt * 16 + m15];
    float sm[4] = {0.f, 0.f, 0.f, 0.f}, sq[4] = {0.f, 0.f, 0.f, 0.f};
    #pragma unroll
    for (int n = 0; n < 8; ++n) {
        int c = wc * 128 + n * 16 + q * 4;
        #pragma unroll
        for (int rt = 0; rt < 4; ++rt) {
            int row = wr * 64 + rt * 16 + m15;
            size_t og = (size_t)(r0 + row) * HID + c;
            float hh[4]; up4(*(const uint2*)&hsrc[og], hh);
            float4 vv = *(const float4*)&vsrc[og];
            const float* vp = &vv.x;
            #pragma unroll
            for (int e = 0; e < 4; ++e) {
                float a = ((acc[n][rt][e] + (float)NNODE * vp[e]) * dv[rt] + hh[e]) * 0.5f;
                acc[n][rt][e] = a;
                sm[rt] += a; sq[rt] += a * a;
            }
        }
    }
    #pragma unroll
    for (int rt = 0; rt < 4; ++rt) {
        sm[rt] += __shfl_xor(sm[rt], 16); sm[rt] += __shfl_xor(sm[rt], 32);
        sq[rt] += __shfl_xor(sq[rt], 16); sq[rt] += __shfl_xor(sq[rt], 32);
    }
    __syncthreads();
    if (lane < 16)
        #pragma unroll
        for (int rt = 0; rt < 4; ++rt) {
            redA[wr * 64 + rt * 16 + m15][wc] = sm[rt];
            redB[wr * 64 + rt * 16 + m15][wc] = sq[rt];
        }
    __syncthreads();
    if (t < 128) {
        float tt = redA[t][0] + redA[t][1] + redA[t][2] + redA[t][3];
        float t2 = redB[t][0] + redB[t][1] + redB[t][2] + redB[t][3];
        float mu = tt * (1.f / HID);
        float rs = rsqrtf(t2 * (1.f / HID) - mu * mu + 1e-5f);
        mu_s[t] = mu; rs_s[t] = rs;
    }
    __syncthreads();
    #pragma unroll
    for (int n = 0; n < 8; ++n) {
        int c = wc * 128 + n * 16 + q * 4;
        float4 g4 = *(const float4*)(lg + c);
        float4 b4 = *(const float4*)(lb + c);
        #pragma unroll
        for (int rt = 0; rt < 4; ++rt) {
            int row = wr * 64 + rt * 16 + m15;
            float mu = mu_s[row], rs = rs_s[row];
            float v0 = (acc[n][rt][0] - mu) * rs * g4.x + b4.x;
            float v1 = (acc[n][rt][1] - mu) * rs * g4.y + b4.y;
            float v2 = (acc[n][rt][2] - mu) * rs * g4.z + b4.z;
            float v3 = (acc[n][rt][3] - mu) * rs * g4.w + b4.w;
            v0 = v0 > 0.f ? v0 : 0.f; v1 = v1 > 0.f ? v1 : 0.f;
            v2 = v2 > 0.f ? v2 : 0.f; v3 = v3 > 0.f ? v3 : 0.f;
            size_t og = (size_t)(r0 + row) * HID + c;
            if (outf) {
                float4 o = {v0, v1, v2, v3};
                *(float4*)&outf[og] = o;
            } else {
                *(uint2*)&outb[og] = pk4(v0, v1, v2, v3);
            }
        }
    }
}

extern "C" void kernel_launch(void* const* d_in, const int* in_sizes, int n_in,
                              void* d_out, int out_size, void* d_ws, size_t ws_size,
                              hipStream_t stream) {
    const float* x    = (const float*)d_in[0];
    const float* fc0w = (const float*)d_in[1];
    const float* fc0b = (const float*)d_in[2];
    const float* ln0g = (const float*)d_in[3];
    const float* ln0b = (const float*)d_in[4];
    const float* q0w  = (const float*)d_in[5];
    const float* k0w  = (const float*)d_in[6];
    const float* v0w  = (const float*)d_in[7];
    const float* ln1g = (const float*)d_in[8];
    const float* ln1b = (const float*)d_in[9];
    const float* q1w  = (const float*)d_in[10];
    const float* k1w  = (const float*)d_in[11];
    const float* v1w  = (const float*)d_in[12];
    const float* ln2g = (const float*)d_in[13];
    const float* ln2b = (const float*)d_in[14];
    // batch (d_in[15]) = repeat(arange(16),4096): argsort == identity. unused.

    // workspace (~247 MB):
    //   H(64M) | Kt(64M, then qhat) | Vt(64M, Xb first) | KVp x4(33.5M) |
    //   KVb(8.4M) | KS | DNV | weights bf16(3.4M)
    // V (fp32 identity) lives in d_out: in-place-safe vs attn2's fp32 out.
    const size_t M64 = (size_t)TNODES * HID * 2;          // 64 MiB
    const size_t PL  = (size_t)NGRAPH * HID * HID * 2;    // 8.39 MB plane
    char* wsc = (char*)d_ws;
    u16*   H   = (u16*)wsc;
    u16*   Kt  = (u16*)(wsc + M64);
    u16*   Vt  = (u16*)(wsc + 2 * M64);
    u16*   KVp = (u16*)(wsc + 3 * M64);
    u16*   KVb = (u16*)(wsc + 3 * M64 + 4 * PL);
    float* KS  = (float*)(wsc + 3 * M64 + 5 * PL);
    float* DNV = KS + NGRAPH * HID;
    u16*   Wc  = (u16*)((char*)DNV + (size_t)TNODES * sizeof(float));
    u16* fc0wb = Wc;
    u16* q0b = Wc + 131072;
    u16* k0b = Wc + 393216;
    u16* v0b = Wc + 655360;
    u16* q1b = Wc + 917504;
    u16* k1b = Wc + 1179648;
    u16* v1b = Wc + 1441792;
    u16* Xb  = Vt;                 // consumed by k_fc before layer-1 proj writes Vt
    u16* QH  = Kt;                 // qhat overwrites Kt after kvmm2 consumed it
    float* V = (float*)d_out;      // fp32 v, in-place-safe vs final fp32 out

    dim3 b256(256), b512(512);
    k_cvt4<<<dim3(64),  b256, 0, stream>>>(fc0w, fc0wb, HID * INCH / 4);
    k_cvt4<<<dim3(64),  b256, 0, stream>>>(q0w, q0b, HID * HID / 4);
    k_cvt4<<<dim3(64),  b256, 0, stream>>>(k0w, k0b, HID * HID / 4);
    k_cvt4<<<dim3(64),  b256, 0, stream>>>(v0w, v0b, HID * HID / 4);
    k_cvt4<<<dim3(64),  b256, 0, stream>>>(q1w, q1b, HID * HID / 4);
    k_cvt4<<<dim3(64),  b256, 0, stream>>>(k1w, k1b, HID * HID / 4);
    k_cvt4<<<dim3(64),  b256, 0, stream>>>(v1w, v1b, HID * HID / 4);
    k_cvt4<<<dim3(1024), b256, 0, stream>>>(x, Xb, TNODES * INCH / 4);

    k_fc<<<dim3(TNODES / 128), b512, 0, stream>>>(Xb, fc0wb, fc0b, ln0g, ln0b, H);

    // ---- layer 1 ----
    k_zero<<<dim3(32), b256, 0, stream>>>(KS, NGRAPH * HID);
    k_proj<<<dim3(TNODES / 128, 2), b512, 0, stream>>>(H, k0b, v0b, Kt, Vt, V, KS);
    k_kvmm2<<<dim3(256), b512, 0, stream>>>(Kt, Vt, KVp);
    k_red4<<<dim3(2048), b256, 0, stream>>>(KVp, KVb, NGRAPH * HID * HID / 8);
    k_qnorm<<<dim3(TNODES / 128), b512, 0, stream>>>(H, q0b, KS, QH, DNV);
    k_attn2<<<dim3(TNODES / 128), b512, 0, stream>>>(QH, KVb, DNV, V, H, ln1g, ln1b,
                                                     H, nullptr);   // H := layer-1 out

    // ---- layer 2 ----
    k_zero<<<dim3(32), b256, 0, stream>>>(KS, NGRAPH * HID);
    k_proj<<<dim3(TNODES / 128, 2), b512, 0, stream>>>(H, k1b, v1b, Kt, Vt, V, KS);
    k_kvmm2<<<dim3(256), b512, 0, stream>>>(Kt, Vt, KVp);
    k_red4<<<dim3(2048), b256, 0, stream>>>(KVp, KVb, NGRAPH * HID * HID / 8);
    k_qnorm<<<dim3(TNODES / 128), b512, 0, stream>>>(H, q1b, KS, QH, DNV);
    k_attn2<<<dim3(TNODES / 128), b512, 0, stream>>>(QH, KVb, DNV, V, H, ln2g, ln2b,
                                                     nullptr, (float*)d_out);
}

// Round 9
// 899.832 us; speedup vs baseline: 1.2004x; 1.1297x over previous
//
#include <hip/hip_runtime.h>

#define TNODES 65536
#define NGRAPH 16
#define NNODE  4096
#define INCH   256
#define HID    512

using u16 = unsigned short;
using u32 = unsigned int;
using v8s = __attribute__((ext_vector_type(8))) short;   // 8 bf16 (4 VGPRs)
using v4f = __attribute__((ext_vector_type(4))) float;   // 4 fp32 acc

__device__ __forceinline__ float bf2f(u16 u) {
    union { u32 i; float f; } v; v.i = ((u32)u) << 16; return v.f;
}
__device__ __forceinline__ u16 f2bf(float f) {
    union { float f; u32 i; } v; v.f = f;
    u32 x = v.i;
    return (u16)((x + 0x7fffu + ((x >> 16) & 1u)) >> 16);
}
__device__ __forceinline__ void up4(uint2 p, float* f) {
    f[0] = __uint_as_float(p.x << 16); f[1] = __uint_as_float(p.x & 0xffff0000u);
    f[2] = __uint_as_float(p.y << 16); f[3] = __uint_as_float(p.y & 0xffff0000u);
}
__device__ __forceinline__ uint2 pk4(float a, float b, float c, float d) {
    uint2 r;
    r.x = (u32)f2bf(a) | ((u32)f2bf(b) << 16);
    r.y = (u32)f2bf(c) | ((u32)f2bf(d) << 16);
    return r;
}

#define MFMA(a, b, c) __builtin_amdgcn_mfma_f32_16x16x32_bf16((a), (b), (c), 0, 0, 0)

// async global->LDS, 16B per lane. dest = wave-uniform base + lane*16 (linear).
#define GLD16(gp, sp) __builtin_amdgcn_global_load_lds( \
    (const __attribute__((address_space(1))) u32*)(const void*)(gp), \
    (__attribute__((address_space(3))) u32*)(void*)(sp), 16, 0, 0)

#define CFENCE() asm volatile("" ::: "memory")

// ---------------- fp32 -> bf16 convert, vectorized ----------------
__global__ void k_cvt4(const float* __restrict__ s, u16* __restrict__ d, int n4) {
    for (int i = blockIdx.x * blockDim.x + threadIdx.x; i < n4; i += gridDim.x * blockDim.x) {
        float4 f = ((const float4*)s)[i];
        ((uint2*)d)[i] = pk4(f.x, f.y, f.z, f.w);
    }
}

// batched weight converts: one launch, blockIdx.y selects the array
struct CvtArgs {
    const float* s[7];
    u16* d[7];
    int n4[7];
};
__global__ void k_cvtw(CvtArgs a) {
    const int y = blockIdx.y;
    const float* s = a.s[y];
    u16* d = a.d[y];
    const int n4 = a.n4[y];
    for (int i = blockIdx.x * blockDim.x + threadIdx.x; i < n4; i += gridDim.x * blockDim.x) {
        float4 f = ((const float4*)s)[i];
        ((uint2*)d)[i] = pk4(f.x, f.y, f.z, f.w);
    }
}

__global__ void k_zero(float* __restrict__ p, int n) {
    int i = blockIdx.x * 256 + threadIdx.x;
    if (i < n) p[i] = 0.f;
}

// ---------------- sum 4 bf16 partial planes -> bf16 ----------------
__global__ void k_red4(const u16* __restrict__ p, u16* __restrict__ o, int n8) {
    const size_t P = (size_t)NGRAPH * HID * HID;
    for (int i = blockIdx.x * blockDim.x + threadIdx.x; i < n8; i += gridDim.x * blockDim.x) {
        size_t b = (size_t)i * 8;
        float s[8] = {0.f, 0.f, 0.f, 0.f, 0.f, 0.f, 0.f, 0.f};
        #pragma unroll
        for (int ss = 0; ss < 4; ++ss) {
            v8s v = *(const v8s*)(p + ss * P + b);
            const u16* vp = (const u16*)&v;
            #pragma unroll
            for (int j = 0; j < 8; ++j) s[j] += bf2f(vp[j]);
        }
        uint2 lo = pk4(s[0], s[1], s[2], s[3]);
        uint2 hi = pk4(s[4], s[5], s[6], s[7]);
        uint4 w; w.x = lo.x; w.y = lo.y; w.z = hi.x; w.w = hi.y;
        *(uint4*)(o + b) = w;
    }
}

// =====================================================================
// GEMM core (round-6 version, best measured 910us): C[128 x 512] =
// Act[128 rows, stride LDK] @ W[512 rows]^T. 512 threads = 8 waves
// (2 row-groups x 4 col-groups), wave tile 64x128 (acc[8][4]). BK=32,
// A and W double-buffered in LDS via global_load_lds(16B), 2-step
// prefetch distance. XOR-swizzle on global source + same on ds_read.
// Counted vmcnt(5). Known-failed variants: per-lane A reg loads (r7,
// -21%), counted vmcnt with drain variants (r4, null), 64-row tile
// (r3/r4, LDS-traffic-limited).
// =====================================================================
template<int LDK, int KLEN>
__device__ __forceinline__ void gemm_core(const u16* __restrict__ A,
                                          const u16* __restrict__ W,
                                          u16* sA, u16* sW, v4f (&acc)[8][4]) {
    const int t = threadIdx.x, lane = t & 63;
    const int q = lane >> 4, m15 = lane & 15;
    const int w = t >> 6, wr = w >> 2, wc = w & 3;

    #pragma unroll
    for (int n = 0; n < 8; ++n)
        #pragma unroll
        for (int rt = 0; rt < 4; ++rt)
            #pragma unroll
            for (int e = 0; e < 4; ++e) acc[n][rt][e] = 0.f;

    int aoff[4], woff[8];
    #pragma unroll
    for (int rt = 0; rt < 4; ++rt) {
        int r = wr * 64 + rt * 16 + m15;
        aoff[rt] = r * 32 + ((q ^ ((r >> 1) & 3)) * 8);
    }
    #pragma unroll
    for (int n = 0; n < 8; ++n) {
        int r = wc * 128 + n * 16 + m15;
        woff[n] = r * 32 + ((q ^ ((r >> 1) & 3)) * 8);
    }

    auto stage = [&](int k0, int buf) {
        u16* dW = sW + buf * (512 * 32);
        #pragma unroll
        for (int p = 0; p < 4; ++p) {
            int sf = p * 512 + t, row = sf >> 2, sl = sf & 3;
            int gc = k0 + ((sl ^ ((row >> 1) & 3)) * 8);
            GLD16(W + (size_t)row * LDK + gc, dW + sf * 8);
        }
        {   // A-tile: 128 rows x 32, one 16B load per thread
            int row = t >> 2, sl = t & 3;
            int gc = k0 + ((sl ^ ((row >> 1) & 3)) * 8);
            GLD16(A + (size_t)row * LDK + gc, sA + buf * (128 * 32) + t * 8);
        }
    };

    const int KT = KLEN / 32;
    stage(0, 0);
    stage(32, 1);
    int cur = 0;
    for (int kt = 0; kt < KT; ++kt) {
        if (kt + 1 < KT) asm volatile("s_waitcnt vmcnt(5)" ::: "memory");
        else             asm volatile("s_waitcnt vmcnt(0)" ::: "memory");
        __builtin_amdgcn_s_barrier();
        CFENCE();
        __builtin_amdgcn_sched_barrier(0);
        const u16* cA = sA + cur * (128 * 32);
        const u16* cW = sW + cur * (512 * 32);
        v8s b[4];
        #pragma unroll
        for (int rt = 0; rt < 4; ++rt) b[rt] = *(const v8s*)(cA + aoff[rt]);
        #pragma unroll
        for (int n = 0; n < 8; ++n) {
            v8s af = *(const v8s*)(cW + woff[n]);
            #pragma unroll
            for (int rt = 0; rt < 4; ++rt)
                acc[n][rt] = MFMA(af, b[rt], acc[n][rt]);
        }
        CFENCE();
        __builtin_amdgcn_s_barrier();
        CFENCE();
        if (kt + 2 < KT) stage((kt + 2) * 32, cur);
        cur ^= 1;
    }
}

// acc element (n,rt,e) <-> A-row wr*64 + rt*16 + (lane&15),
//                          W-row wc*128 + n*16 + (lane>>4)*4 + e.

// transpose swizzle: X(c) = (((c>>2)&3)<<4) ^ ((c&3)<<3)
__device__ __forceinline__ int tswz(int c) {
    return (((c >> 2) & 3) << 4) ^ ((c & 3) << 3);
}

// smem: 16KB sA dbuf + 64KB sW dbuf = 80KB -> 2 blocks/CU.
// Epilogue scratch aliases the sA region (dead after the GEMM's final barrier).
#define SMEM_DECL __shared__ char smem[81920]
#define SA ((u16*)smem)
#define SW ((u16*)(smem + 16384))

// ---------------- fc0 + LN + ReLU ----------------
__launch_bounds__(512, 2)
__global__ void k_fc(const u16* __restrict__ xb, const u16* __restrict__ wb,
                     const float* __restrict__ bias, const float* __restrict__ lg,
                     const float* __restrict__ lb, u16* __restrict__ h) {
    SMEM_DECL;
    float (*redA)[4] = (float(*)[4])smem;              // [128][4]
    float (*redB)[4] = (float(*)[4])(smem + 2048);     // [128][4]
    float* mu_s = (float*)(smem + 4096);               // [128]
    float* rs_s = (float*)(smem + 4608);               // [128]
    const int t = threadIdx.x, lane = t & 63, w = t >> 6;
    const int q = lane >> 4, m15 = lane & 15;
    const int wr = w >> 2, wc = w & 3;
    const int bx = (int)blockIdx.x;
    const int swz = (bx & 7) * ((int)gridDim.x >> 3) + (bx >> 3);
    const int r0 = swz * 128;
    v4f acc[8][4];
    gemm_core<INCH, INCH>(xb + (size_t)r0 * INCH, wb, SA, SW, acc);

    float sm[4] = {0.f, 0.f, 0.f, 0.f}, sq[4] = {0.f, 0.f, 0.f, 0.f};
    #pragma unroll
    for (int n = 0; n < 8; ++n) {
        int c = wc * 128 + n * 16 + q * 4;
        float4 bi = *(const float4*)(bias + c);
        const float* bp = &bi.x;
        #pragma unroll
        for (int rt = 0; rt < 4; ++rt)
            #pragma unroll
            for (int e = 0; e < 4; ++e) {
                float a = acc[n][rt][e] + bp[e];
                acc[n][rt][e] = a;
                sm[rt] += a; sq[rt] += a * a;
            }
    }
    #pragma unroll
    for (int rt = 0; rt < 4; ++rt) {
        sm[rt] += __shfl_xor(sm[rt], 16); sm[rt] += __shfl_xor(sm[rt], 32);
        sq[rt] += __shfl_xor(sq[rt], 16); sq[rt] += __shfl_xor(sq[rt], 32);
    }
    if (lane < 16)
        #pragma unroll
        for (int rt = 0; rt < 4; ++rt) {
            redA[wr * 64 + rt * 16 + m15][wc] = sm[rt];
            redB[wr * 64 + rt * 16 + m15][wc] = sq[rt];
        }
    __syncthreads();
    if (t < 128) {
        float tt = redA[t][0] + redA[t][1] + redA[t][2] + redA[t][3];
        float t2 = redB[t][0] + redB[t][1] + redB[t][2] + redB[t][3];
        float mu = tt * (1.f / HID);
        float rs = rsqrtf(t2 * (1.f / HID) - mu * mu + 1e-5f);
        mu_s[t] = mu; rs_s[t] = rs;
    }
    __syncthreads();
    #pragma unroll
    for (int n = 0; n < 8; ++n) {
        int c = wc * 128 + n * 16 + q * 4;
        float4 g4 = *(const float4*)(lg + c);
        float4 b4 = *(const float4*)(lb + c);
        #pragma unroll
        for (int rt = 0; rt < 4; ++rt) {
            int row = wr * 64 + rt * 16 + m15;
            float mu = mu_s[row], rs = rs_s[row];
            float v0 = (acc[n][rt][0] - mu) * rs * g4.x + b4.x;
            float v1 = (acc[n][rt][1] - mu) * rs * g4.y + b4.y;
            float v2 = (acc[n][rt][2] - mu) * rs * g4.z + b4.z;
            float v3 = (acc[n][rt][3] - mu) * rs * g4.w + b4.w;
            v0 = v0 > 0.f ? v0 : 0.f; v1 = v1 > 0.f ? v1 : 0.f;
            v2 = v2 > 0.f ? v2 : 0.f; v3 = v3 > 0.f ? v3 : 0.f;
            *(uint2*)&h[(size_t)(r0 + row) * HID + c] = pk4(v0, v1, v2, v3);
        }
    }
}

// ---------------- k/v projection + transposed outputs ----------------
// y==0: k -> eps + L2 row-normalize -> Kt[g][m][l] bf16, fused ks partials.
// y==1: v -> Vt[g][d][l] bf16 only (attn2 reads Vt; no fp32 V copy -- r8
//        showed restoring it regresses).
__launch_bounds__(512, 2)
__global__ void k_proj(const u16* __restrict__ hsrc, const u16* __restrict__ wkb,
                       const u16* __restrict__ wvb, u16* __restrict__ kt,
                       u16* __restrict__ vt, float* __restrict__ ksum) {
    SMEM_DECL;
    float (*red)[4] = (float(*)[4])smem;               // [128][4]
    float* rowv = (float*)(smem + 2048);               // [128]
    u16* sT = SW;                                      // 512 ch x 64 rows
    const int t = threadIdx.x, lane = t & 63, w = t >> 6;
    const int q = lane >> 4, m15 = lane & 15;
    const int wr = w >> 2, wc = w & 3;
    const int bx = (int)blockIdx.x;
    const int swz = (bx & 7) * ((int)gridDim.x >> 3) + (bx >> 3);
    const int r0 = swz * 128;
    const int g = swz >> 5;                   // 32 blocks per graph
    const int lbase = (swz & 31) * 128;
    const int mode = blockIdx.y;
    v4f acc[8][4];
    gemm_core<HID, HID>(hsrc + (size_t)r0 * HID, mode ? wvb : wkb, SA, SW, acc);

    const int ch = t;
    const int xs = (((ch >> 2) & 3) << 1) ^ (ch & 3);   // tswz(ch)>>3
    if (mode == 0) {
        float sq[4] = {0.f, 0.f, 0.f, 0.f};
        #pragma unroll
        for (int n = 0; n < 8; ++n)
            #pragma unroll
            for (int rt = 0; rt < 4; ++rt)
                #pragma unroll
                for (int e = 0; e < 4; ++e) {
                    float vv = acc[n][rt][e];
                    if (vv == 0.f) vv = 1e-6f;
                    acc[n][rt][e] = vv;
                    sq[rt] += vv * vv;
                }
        #pragma unroll
        for (int rt = 0; rt < 4; ++rt) {
            sq[rt] += __shfl_xor(sq[rt], 16); sq[rt] += __shfl_xor(sq[rt], 32);
        }
        if (lane < 16)
            #pragma unroll
            for (int rt = 0; rt < 4; ++rt)
                red[wr * 64 + rt * 16 + m15][wc] = sq[rt];
        __syncthreads();
        if (t < 128)
            rowv[t] = rsqrtf(red[t][0] + red[t][1] + red[t][2] + red[t][3]);
        __syncthreads();
        float sum = 0.f;
        #pragma unroll
        for (int pass = 0; pass < 2; ++pass) {
            if (wr == pass) {
                #pragma unroll
                for (int n = 0; n < 8; ++n)
                    #pragma unroll
                    for (int rt = 0; rt < 4; ++rt) {
                        int rl = rt * 16 + m15;           // row within pass
                        float rn = rowv[wr * 64 + rl];
                        #pragma unroll
                        for (int e = 0; e < 4; ++e) {
                            int c = wc * 128 + n * 16 + q * 4 + e;
                            sT[(c << 6) + (rl ^ tswz(c))] = f2bf(acc[n][rt][e] * rn);
                        }
                    }
            }
            __syncthreads();
            u16* op = kt + ((size_t)(g * 512 + ch)) * NNODE + lbase + pass * 64;
            #pragma unroll
            for (int jj = 0; jj < 8; ++jj) {
                v8s cvec = *(const v8s*)&sT[(ch << 6) + jj * 8];
                int l0 = (jj ^ xs) * 8;
                *(v8s*)(op + l0) = cvec;
                const u16* cp = (const u16*)&cvec;
                #pragma unroll
                for (int i = 0; i < 8; ++i) sum += bf2f(cp[i]);
            }
            __syncthreads();
        }
        atomicAdd(&ksum[g * 512 + ch], sum);
    } else {
        #pragma unroll
        for (int pass = 0; pass < 2; ++pass) {
            if (wr == pass) {
                #pragma unroll
                for (int n = 0; n < 8; ++n)
                    #pragma unroll
                    for (int rt = 0; rt < 4; ++rt) {
                        int rl = rt * 16 + m15;
                        #pragma unroll
                        for (int e = 0; e < 4; ++e) {
                            int c = wc * 128 + n * 16 + q * 4 + e;
                            sT[(c << 6) + (rl ^ tswz(c))] = f2bf(acc[n][rt][e]);
                        }
                    }
            }
            __syncthreads();
            u16* op = vt + ((size_t)(g * 512 + ch)) * NNODE + lbase + pass * 64;
            #pragma unroll
            for (int jj = 0; jj < 8; ++jj) {
                v8s cvec = *(const v8s*)&sT[(ch << 6) + jj * 8];
                int l0 = (jj ^ xs) * 8;
                *(v8s*)(op + l0) = cvec;
            }
            __syncthreads();
        }
    }
}

// ---------------- kvmm2 body: kvsT partial[s] = Vt[s-chunk] @ Kt^T ----------
__device__ __forceinline__ void kvmm2_body(int bx, char* smemp,
        const u16* __restrict__ kt, const u16* __restrict__ vt,
        u16* __restrict__ kvp) {
    u16* sA = (u16*)smemp;
    u16* sW = (u16*)(smemp + 16384);
    const int t = threadIdx.x, lane = t & 63, w = t >> 6;
    const int q = lane >> 4, m15 = lane & 15;
    const int wr = w >> 2, wc = w & 3;
    const int swz = (bx & 7) * 32 + (bx >> 3);   // 256 blocks, 32/XCD chunk
    const int db = swz & 3, s = (swz >> 2) & 3, g = swz >> 4;
    const u16* A = vt + ((size_t)(g * 512 + db * 128)) * NNODE + s * 1024;
    const u16* W = kt + ((size_t)(g * 512)) * NNODE + s * 1024;
    v4f acc[8][4];
    gemm_core<NNODE, 1024>(A, W, sA, sW, acc);
    u16* plane = kvp + (size_t)s * NGRAPH * HID * HID;
    #pragma unroll
    for (int n = 0; n < 8; ++n) {
        int m = wc * 128 + n * 16 + q * 4;
        #pragma unroll
        for (int rt = 0; rt < 4; ++rt) {
            int d = db * 128 + wr * 64 + rt * 16 + m15;
            *(uint2*)&plane[((size_t)(g * 512) + d) * 512 + m] =
                pk4(acc[n][rt][0], acc[n][rt][1], acc[n][rt][2], acc[n][rt][3]);
        }
    }
}

// ---------------- qnorm body: q projection + normalize + denom -------------
__device__ __forceinline__ void qnorm_body(int bx, char* smemp,
        const u16* __restrict__ hsrc, const u16* __restrict__ qwb,
        const float* __restrict__ ks, u16* __restrict__ qo,
        float* __restrict__ dnv) {
    u16* sA = (u16*)smemp;
    u16* sW = (u16*)(smemp + 16384);
    float (*redA)[4] = (float(*)[4])smemp;             // ss (aliases sA)
    float (*redB)[4] = (float(*)[4])(smemp + 2048);    // ws
    float* rowv = (float*)(smemp + 4096);              // rn
    const int t = threadIdx.x, lane = t & 63, w = t >> 6;
    const int q = lane >> 4, m15 = lane & 15;
    const int wr = w >> 2, wc = w & 3;
    const int swz = (bx & 7) * 64 + (bx >> 3);         // 512 blocks
    const int r0 = swz * 128;
    const int gi = swz >> 5;            // 32 blocks per graph
    v4f acc[8][4];
    gemm_core<HID, HID>(hsrc + (size_t)r0 * HID, qwb, sA, sW, acc);

    float ss[4] = {0.f, 0.f, 0.f, 0.f}, ws[4] = {0.f, 0.f, 0.f, 0.f};
    #pragma unroll
    for (int n = 0; n < 8; ++n) {
        int c = wc * 128 + n * 16 + q * 4;
        float4 kv = *(const float4*)(ks + (gi << 9) + c);
        const float* kp = &kv.x;
        #pragma unroll
        for (int rt = 0; rt < 4; ++rt)
            #pragma unroll
            for (int e = 0; e < 4; ++e) {
                float vv = acc[n][rt][e];
                if (vv == 0.f) vv = 1e-6f;
                acc[n][rt][e] = vv;
                ss[rt] += vv * vv; ws[rt] += vv * kp[e];
            }
    }
    #pragma unroll
    for (int rt = 0; rt < 4; ++rt) {
        ss[rt] += __shfl_xor(ss[rt], 16); ss[rt] += __shfl_xor(ss[rt], 32);
        ws[rt] += __shfl_xor(ws[rt], 16); ws[rt] += __shfl_xor(ws[rt], 32);
    }
    if (lane < 16)
        #pragma unroll
        for (int rt = 0; rt < 4; ++rt) {
            redA[wr * 64 + rt * 16 + m15][wc] = ss[rt];
            redB[wr * 64 + rt * 16 + m15][wc] = ws[rt];
        }
    __syncthreads();
    if (t < 128) {
        float st = redA[t][0] + redA[t][1] + redA[t][2] + redA[t][3];
        float wt = redB[t][0] + redB[t][1] + redB[t][2] + redB[t][3];
        float rn = rsqrtf(st);
        rowv[t] = rn;
        dnv[r0 + t] = 1.f / (rn * wt + (float)NNODE);
    }
    __syncthreads();
    #pragma unroll
    for (int n = 0; n < 8; ++n) {
        int c = wc * 128 + n * 16 + q * 4;
        #pragma unroll
        for (int rt = 0; rt < 4; ++rt) {
            int row = wr * 64 + rt * 16 + m15;
            float rn = rowv[row];
            *(uint2*)&qo[(size_t)(r0 + row) * HID + c] =
                pk4(acc[n][rt][0] * rn, acc[n][rt][1] * rn,
                    acc[n][rt][2] * rn, acc[n][rt][3] * rn);
        }
    }
}

__launch_bounds__(512, 2)
__global__ void k_kvmm2(const u16* __restrict__ kt, const u16* __restrict__ vt,
                        u16* __restrict__ kvp) {
    SMEM_DECL;
    kvmm2_body((int)blockIdx.x, smem, kt, vt, kvp);
}

__launch_bounds__(512, 2)
__global__ void k_qnorm(const u16* __restrict__ hsrc, const u16* __restrict__ qwb,
                        const float* __restrict__ ks, u16* __restrict__ qo,
                        float* __restrict__ dnv) {
    SMEM_DECL;
    qnorm_body((int)blockIdx.x, smem, hsrc, qwb, ks, qo, dnv);
}

// merged launch: kvmm2 (256 blocks, first -- they run ~2x longer) + qnorm
// (512 blocks). kvmm2 alone fills only half the machine (256 blocks on 512
// block-slots); co-scheduling with the independent qnorm keeps CUs busy.
// Requires qo != kt (kvmm2 reads Kt concurrently) -> dedicated QH buffer.
__launch_bounds__(512, 2)
__global__ void k_mq(const u16* __restrict__ kt, const u16* __restrict__ vt,
                     u16* __restrict__ kvp, const u16* __restrict__ hsrc,
                     const u16* __restrict__ qwb, const float* __restrict__ ks,
                     u16* __restrict__ qo, float* __restrict__ dnv) {
    SMEM_DECL;
    const int bx = (int)blockIdx.x;
    if (bx < 256) kvmm2_body(bx, smem, kt, vt, kvp);
    else          qnorm_body(bx - 256, smem, hsrc, qwb, ks, qo, dnv);
}

// ---------------- num = qhat @ kvsT^T + residual + LN + ReLU ----------------
// v from transposed bf16 Vt (scalar u16 loads, 16-lane-contiguous segments).
__launch_bounds__(512, 2)
__global__ void k_attn2(const u16* __restrict__ qhat, const u16* __restrict__ kvstb,
                        const float* __restrict__ dnv, const u16* __restrict__ vt,
                        const u16* __restrict__ hsrc, const float* __restrict__ lg,
                        const float* __restrict__ lb, u16* __restrict__ outb,
                        float* __restrict__ outf) {
    SMEM_DECL;
    float (*redA)[4] = (float(*)[4])smem;
    float (*redB)[4] = (float(*)[4])(smem + 2048);
    float* mu_s = (float*)(smem + 4096);
    float* rs_s = (float*)(smem + 4608);
    const int t = threadIdx.x, lane = t & 63, w = t >> 6;
    const int q = lane >> 4, m15 = lane & 15;
    const int wr = w >> 2, wc = w & 3;
    const int bx = (int)blockIdx.x;
    const int swz = (bx & 7) * ((int)gridDim.x >> 3) + (bx >> 3);
    const int r0 = swz * 128;
    const int gi = swz >> 5;
    v4f acc[8][4];
    gemm_core<HID, HID>(qhat + (size_t)r0 * HID, kvstb + (size_t)gi * HID * HID,
                        SA, SW, acc);

    float dv[4];
    #pragma unroll
    for (int rt = 0; rt < 4; ++rt) dv[rt] = dnv[r0 + wr * 64 + rt * 16 + m15];
    const u16* vtg = vt + (size_t)(gi * 512) * NNODE + ((swz & 31) * 128 + wr * 64 + m15);
    float sm[4] = {0.f, 0.f, 0.f, 0.f}, sq[4] = {0.f, 0.f, 0.f, 0.f};
    #pragma unroll
    for (int n = 0; n < 8; ++n) {
        int c = wc * 128 + n * 16 + q * 4;
        const u16* vb = vtg + (size_t)c * NNODE;
        #pragma unroll
        for (int rt = 0; rt < 4; ++rt) {
            int row = wr * 64 + rt * 16 + m15;
            size_t og = (size_t)(r0 + row) * HID + c;
            float hh[4]; up4(*(const uint2*)&hsrc[og], hh);
            #pragma unroll
            for (int e = 0; e < 4; ++e) {
                float vv = bf2f(vb[(size_t)e * NNODE + rt * 16]);
                float a = ((acc[n][rt][e] + (float)NNODE * vv) * dv[rt] + hh[e]) * 0.5f;
                acc[n][rt][e] = a;
                sm[rt] += a; sq[rt] += a * a;
            }
        }
    }
    #pragma unroll
    for (int rt = 0; rt < 4; ++rt) {
        sm[rt] += __shfl_xor(sm[rt], 16); sm[rt] += __shfl_xor(sm[rt], 32);
        sq[rt] += __shfl_xor(sq[rt], 16); sq[rt] += __shfl_xor(sq[rt], 32);
    }
    if (lane < 16)
        #pragma unroll
        for (int rt = 0; rt < 4; ++rt) {
            redA[wr * 64 + rt * 16 + m15][wc] = sm[rt];
            redB[wr * 64 + rt * 16 + m15][wc] = sq[rt];
        }
    __syncthreads();
    if (t < 128) {
        float tt = redA[t][0] + redA[t][1] + redA[t][2] + redA[t][3];
        float t2 = redB[t][0] + redB[t][1] + redB[t][2] + redB[t][3];
        float mu = tt * (1.f / HID);
        float rs = rsqrtf(t2 * (1.f / HID) - mu * mu + 1e-5f);
        mu_s[t] = mu; rs_s[t] = rs;
    }
    __syncthreads();
    #pragma unroll
    for (int n = 0; n < 8; ++n) {
        int c = wc * 128 + n * 16 + q * 4;
        float4 g4 = *(const float4*)(lg + c);
        float4 b4 = *(const float4*)(lb + c);
        #pragma unroll
        for (int rt = 0; rt < 4; ++rt) {
            int row = wr * 64 + rt * 16 + m15;
            float mu = mu_s[row], rs = rs_s[row];
            float v0 = (acc[n][rt][0] - mu) * rs * g4.x + b4.x;
            float v1 = (acc[n][rt][1] - mu) * rs * g4.y + b4.y;
            float v2 = (acc[n][rt][2] - mu) * rs * g4.z + b4.z;
            float v3 = (acc[n][rt][3] - mu) * rs * g4.w + b4.w;
            v0 = v0 > 0.f ? v0 : 0.f; v1 = v1 > 0.f ? v1 : 0.f;
            v2 = v2 > 0.f ? v2 : 0.f; v3 = v3 > 0.f ? v3 : 0.f;
            size_t og = (size_t)(r0 + row) * HID + c;
            if (outf) {
                float4 o = {v0, v1, v2, v3};
                *(float4*)&outf[og] = o;
            } else {
                *(uint2*)&outb[og] = pk4(v0, v1, v2, v3);
            }
        }
    }
}

extern "C" void kernel_launch(void* const* d_in, const int* in_sizes, int n_in,
                              void* d_out, int out_size, void* d_ws, size_t ws_size,
                              hipStream_t stream) {
    const float* x    = (const float*)d_in[0];
    const float* fc0w = (const float*)d_in[1];
    const float* fc0b = (const float*)d_in[2];
    const float* ln0g = (const float*)d_in[3];
    const float* ln0b = (const float*)d_in[4];
    const float* q0w  = (const float*)d_in[5];
    const float* k0w  = (const float*)d_in[6];
    const float* v0w  = (const float*)d_in[7];
    const float* ln1g = (const float*)d_in[8];
    const float* ln1b = (const float*)d_in[9];
    const float* q1w  = (const float*)d_in[10];
    const float* k1w  = (const float*)d_in[11];
    const float* v1w  = (const float*)d_in[12];
    const float* ln2g = (const float*)d_in[13];
    const float* ln2b = (const float*)d_in[14];
    // batch (d_in[15]) = repeat(arange(16),4096): argsort == identity. unused.

    const size_t M64 = (size_t)TNODES * HID * 2;          // 64 MiB
    const size_t PL  = (size_t)NGRAPH * HID * HID * 2;    // 8.39 MB plane
    const size_t KS_SZ  = (size_t)NGRAPH * HID * sizeof(float);
    const size_t DNV_SZ = (size_t)TNODES * sizeof(float);
    const size_t WC_SZ  = (size_t)1703936 * 2;
    const size_t NEED_BIG = 4 * M64 + 5 * PL + KS_SZ + DNV_SZ + WC_SZ;
    const bool bigws = ws_size >= NEED_BIG;

    char* p = (char*)d_ws;
    u16*   H   = (u16*)p;  p += M64;
    u16*   Kt  = (u16*)p;  p += M64;
    u16*   Vt  = (u16*)p;  p += M64;
    u16*   QHb = nullptr;
    if (bigws) { QHb = (u16*)p; p += M64; }               // dedicated qhat
    u16*   KVp = (u16*)p;  p += 4 * PL;
    u16*   KVb = (u16*)p;  p += PL;
    float* KS  = (float*)p; p += KS_SZ;
    float* DNV = (float*)p; p += DNV_SZ;
    u16*   Wc  = (u16*)p;
    u16* fc0wb = Wc;
    u16* q0b = Wc + 131072;
    u16* k0b = Wc + 393216;
    u16* v0b = Wc + 655360;
    u16* q1b = Wc + 917504;
    u16* k1b = Wc + 1179648;
    u16* v1b = Wc + 1441792;
    u16* Xb  = Vt;                 // consumed by k_fc before layer-1 proj writes Vt
    u16* QH  = bigws ? QHb : Kt;   // fallback: qhat overwrites Kt (serial only)

    dim3 b256(256), b512(512);
    // weight converts: one batched launch; x convert: one launch
    CvtArgs ca;
    ca.s[0] = fc0w; ca.d[0] = fc0wb; ca.n4[0] = HID * INCH / 4;
    ca.s[1] = q0w;  ca.d[1] = q0b;   ca.n4[1] = HID * HID / 4;
    ca.s[2] = k0w;  ca.d[2] = k0b;   ca.n4[2] = HID * HID / 4;
    ca.s[3] = v0w;  ca.d[3] = v0b;   ca.n4[3] = HID * HID / 4;
    ca.s[4] = q1w;  ca.d[4] = q1b;   ca.n4[4] = HID * HID / 4;
    ca.s[5] = k1w;  ca.d[5] = k1b;   ca.n4[5] = HID * HID / 4;
    ca.s[6] = v1w;  ca.d[6] = v1b;   ca.n4[6] = HID * HID / 4;
    k_cvtw<<<dim3(64, 7), b256, 0, stream>>>(ca);
    k_cvt4<<<dim3(1024), b256, 0, stream>>>(x, Xb, TNODES * INCH / 4);

    k_fc<<<dim3(TNODES / 128), b512, 0, stream>>>(Xb, fc0wb, fc0b, ln0g, ln0b, H);

    // ---- layer 1 ----
    k_zero<<<dim3(32), b256, 0, stream>>>(KS, NGRAPH * HID);
    k_proj<<<dim3(TNODES / 128, 2), b512, 0, stream>>>(H, k0b, v0b, Kt, Vt, KS);
    if (bigws) {
        k_mq<<<dim3(768), b512, 0, stream>>>(Kt, Vt, KVp, H, q0b, KS, QH, DNV);
    } else {
        k_kvmm2<<<dim3(256), b512, 0, stream>>>(Kt, Vt, KVp);
        k_qnorm<<<dim3(512), b512, 0, stream>>>(H, q0b, KS, QH, DNV);
    }
    k_red4<<<dim3(2048), b256, 0, stream>>>(KVp, KVb, NGRAPH * HID * HID / 8);
    k_attn2<<<dim3(TNODES / 128), b512, 0, stream>>>(QH, KVb, DNV, Vt, H, ln1g, ln1b,
                                                     H, nullptr);   // H := layer-1 out

    // ---- layer 2 ----
    k_zero<<<dim3(32), b256, 0, stream>>>(KS, NGRAPH * HID);
    k_proj<<<dim3(TNODES / 128, 2), b512, 0, stream>>>(H, k1b, v1b, Kt, Vt, KS);
    if (bigws) {
        k_mq<<<dim3(768), b512, 0, stream>>>(Kt, Vt, KVp, H, q1b, KS, QH, DNV);
    } else {
        k_kvmm2<<<dim3(256), b512, 0, stream>>>(Kt, Vt, KVp);
        k_qnorm<<<dim3(512), b512, 0, stream>>>(H, q1b, KS, QH, DNV);
    }
    k_red4<<<dim3(2048), b256, 0, stream>>>(KVp, KVb, NGRAPH * HID * HID / 8);
    k_attn2<<<dim3(TNODES / 128), b512, 0, stream>>>(QH, KVb, DNV, Vt, H, ln2g, ln2b,
                                                     nullptr, (float*)d_out);
}